// Round 4
// baseline (280.613 us; speedup 1.0000x reference)
//
#include <hip/hip_runtime.h>
#include <math.h>

#define NB 64
#define LIN 4001
#define LC 998
#define ND 1000
#define EPSBN 1e-5f

#define CKL 100          // K-chunk for QKV GEMM -> 10 chunks * 3 * 16 = 480 blocks
#define NCHL 10
#define CKO 50           // K-chunk for out GEMM -> 20 chunks * 16 = 320 blocks
#define NCHO 20

// ws float offsets (accumulators seeded with biases by k_bnconv)
#define OFF_CONVT 0u          // 3*998*64 = 191616
#define OFF_Q     191616u     // 64*1000  = 64000
#define OFF_KV    255616u     // 64*2048  = 131072
#define OFF_CF    386688u     // 1000*64  = 64000
// end = 450688 floats = 1.8 MB

// ---------------- K1: fused BatchNorm + strided conv -> convT[w][j][b] ------
// Also seeds the q/kv/out accumulators with their biases (split-K atomics
// from k_lin/k_out land on top of these; stream order guarantees seeding
// completes first).
__global__ __launch_bounds__(256) void k_bnconv(
    const float* __restrict__ x,
    const float* __restrict__ g, const float* __restrict__ be,
    const float* __restrict__ mu, const float* __restrict__ va,
    const float* __restrict__ cwq, const float* __restrict__ cbq,
    const float* __restrict__ cwk, const float* __restrict__ cbk,
    const float* __restrict__ cwv, const float* __restrict__ cbv,
    const float* __restrict__ lbq, const float* __restrict__ lbk,
    const float* __restrict__ lbv, const float* __restrict__ outb,
    float* __restrict__ convT,
    float* __restrict__ q, float* __restrict__ kv, float* __restrict__ out)
{
    int tid = threadIdx.x;
    int jt  = blockIdx.x;
    int b   = blockIdx.y;

    // seed accumulators (250 elems per block, 4 blocks cover 1000)
    if (tid < 250) {
        int e = jt * 250 + tid;
        q[(size_t)b * ND + e] = lbq[e];
        *(float2*)&kv[(size_t)b * 2048 + 2 * e] = make_float2(lbk[e], lbv[e]);
        out[(size_t)b * ND + e] = outb[e];
    }

    int j = jt * 256 + tid;
    if (j < LC) {
        const float* xb = x + (size_t)b * LIN + 4 * j;
        float aq = 0.f, ak = 0.f, av = 0.f;
#pragma unroll
        for (int t = 0; t < 10; ++t) {
            int i = 4 * j + t;
            float s  = g[i] * rsqrtf(va[i] + EPSBN);
            float xn = (xb[t] - mu[i]) * s + be[i];
            aq = fmaf(xn, cwq[t], aq);
            ak = fmaf(xn, cwk[t], ak);
            av = fmaf(xn, cwv[t], av);
        }
        convT[((size_t)0 * LC + j) * 64 + b] = aq + cbq[0];
        convT[((size_t)1 * LC + j) * 64 + b] = ak + cbk[0];
        convT[((size_t)2 * LC + j) * 64 + b] = av + cbv[0];
    }
}

// ---------------- shared GEMM microtile body (64b x 64d x CKT) --------------
// Split-K: the reduced 64x64 tile is atomically accumulated into
// obase[bb*rowst + col*cstr + coff] (guarded col < ND).
template <int CKT>
__device__ __forceinline__ void gemm_tile(
    const float* __restrict__ Asrc,   // [jc][64] chunk, b-contiguous
    const float* __restrict__ Brow,   // weight base, row stride ldB
    int ldB, int dgb, int j0, int jc,
    float* __restrict__ obase, int rowst, int cstr, int coff,
    float* lds)
{
    constexpr int LDW = CKT + 1;
    constexpr int F2R = CKT / 2;
    float* ldsC = lds;                // [CKT][64]
    float* ldsW = lds + CKT * 64;     // [64][LDW]
    int tid  = threadIdx.x;
    int lane = tid & 63;
    int w    = tid >> 6;
    int b0   = (lane & 7) << 3;
    int d0   = (lane >> 3) << 3;

    {   // stage A chunk via float4 (fully coalesced)
        const float4* src = (const float4*)Asrc;
        float4* dst = (float4*)ldsC;
        int n = jc * 16;
        for (int t = tid; t < n; t += 256) dst[t] = src[t];
    }
    // stage B tile via float2 (row starts & j0 are even)
    for (int idx = tid; idx < 64 * F2R; idx += 256) {
        int dd = idx / F2R, j2 = idx % F2R;
        int dg = dgb + dd;
        float2 v = make_float2(0.f, 0.f);
        if (dg < ND && 2 * j2 < jc)
            v = *(const float2*)(Brow + (size_t)dg * ldB + j0 + 2 * j2);
        ldsW[dd * LDW + 2 * j2]     = v.x;
        ldsW[dd * LDW + 2 * j2 + 1] = v.y;
    }
    __syncthreads();

    float acc[8][8];
#pragma unroll
    for (int i = 0; i < 8; ++i)
#pragma unroll
        for (int jx = 0; jx < 8; ++jx) acc[i][jx] = 0.f;

    int js = (jc * w) >> 2;
    int je = (jc * (w + 1)) >> 2;
    for (int jj = js; jj < je; ++jj) {
        float4 c0 = *(const float4*)(ldsC + jj * 64 + b0);
        float4 c1 = *(const float4*)(ldsC + jj * 64 + b0 + 4);
        float cv[8] = {c0.x, c0.y, c0.z, c0.w, c1.x, c1.y, c1.z, c1.w};
        float wv[8];
#pragma unroll
        for (int r = 0; r < 8; ++r) wv[r] = ldsW[(d0 + r) * LDW + jj];
#pragma unroll
        for (int i = 0; i < 8; ++i)
#pragma unroll
            for (int jx = 0; jx < 8; ++jx)
                acc[i][jx] = fmaf(cv[i], wv[jx], acc[i][jx]);
    }
    __syncthreads();   // done with staged data; reuse LDS for reduce

    // two passes (f4 halves of each lane's d-range); per-wave buf [64][36]
    for (int p = 0; p < 2; ++p) {
        float* red = lds + w * 2304;
#pragma unroll
        for (int i = 0; i < 8; ++i)
            *(float4*)(red + (b0 + i) * 36 + (d0 >> 1)) =
                make_float4(acc[i][4*p], acc[i][4*p+1], acc[i][4*p+2], acc[i][4*p+3]);
        __syncthreads();
        for (int t = tid; t < 512; t += 256) {
            int bb = t >> 3, gg = t & 7;
            int o = bb * 36 + 4 * gg;
            float4 a0 = *(const float4*)(lds + o);
            float4 a1 = *(const float4*)(lds + 2304 + o);
            float4 a2 = *(const float4*)(lds + 4608 + o);
            float4 a3 = *(const float4*)(lds + 6912 + o);
            float4 s;
            s.x = a0.x + a1.x + a2.x + a3.x;
            s.y = a0.y + a1.y + a2.y + a3.y;
            s.z = a0.z + a1.z + a2.z + a3.z;
            s.w = a0.w + a1.w + a2.w + a3.w;
            int col = dgb + 8 * gg + 4 * p;
            float* row = obase + (size_t)bb * rowst;
            if (col     < ND) atomicAdd(row + (size_t)(col    ) * cstr + coff, s.x);
            if (col + 1 < ND) atomicAdd(row + (size_t)(col + 1) * cstr + coff, s.y);
            if (col + 2 < ND) atomicAdd(row + (size_t)(col + 2) * cstr + coff, s.z);
            if (col + 3 < ND) atomicAdd(row + (size_t)(col + 3) * cstr + coff, s.w);
        }
        __syncthreads();
    }
}

// ---------------- K2: QKV GEMM split-K -> atomic into q / kv ----------------
__global__ __launch_bounds__(256) void k_lin(
    const float* __restrict__ convT,
    const float* __restrict__ lwq, const float* __restrict__ lwk,
    const float* __restrict__ lwv,
    float* __restrict__ q, float* __restrict__ kv)
{
    __shared__ float lds[12864];
    int dgx   = blockIdx.x;
    int which = blockIdx.y;
    int chunk = blockIdx.z;
    int j0 = chunk * CKL;
    int jc = (LC - j0 < CKL) ? (LC - j0) : CKL;
    const float* lw = (which == 0) ? lwq : ((which == 1) ? lwk : lwv);
    const float* Asrc = convT + ((size_t)which * LC + j0) * 64;
    float* obase; int rowst, cstr, coff;
    if (which == 0) { obase = q;  rowst = ND;   cstr = 1; coff = 0; }
    else            { obase = kv; rowst = 2048; cstr = 2; coff = which - 1; }
    gemm_tile<CKL>(Asrc, lw, LC, dgx * 64, j0, jc, obase, rowst, cstr, coff, lds);
}

// ---------------- K3: attention (1024 blocks), act applied inline -----------
__global__ __launch_bounds__(256) void k_attn(
    const float* __restrict__ q, const float* __restrict__ kv,
    const float* __restrict__ ipw, const float* __restrict__ ipb,
    const float* __restrict__ opw, const float* __restrict__ opb,
    float* __restrict__ cfT)
{
    __shared__ float ldsKV[2048];
    __shared__ float sden[256];
    __shared__ float snum[256];
    __shared__ float rmax[4];
    __shared__ float rmin[4];
    int tid = threadIdx.x;
    int b   = blockIdx.y;
    int w   = tid >> 6;
    int ii  = tid & 63;
    int i   = blockIdx.x * 64 + ii;

    {   // stage kv[b] applying ReLU + in_proj on the fly
        const float2* src = (const float2*)(kv + (size_t)b * 2048);
        float2* dst = (float2*)ldsKV;
        float w1 = ipw[1], b1 = ipb[1], w2 = ipw[2], b2 = ipb[2];
        for (int t = tid; t < 1024; t += 256) {
            float2 rv = src[t];
            dst[t] = make_float2(fmaf(fmaxf(rv.x, 0.f), w1, b1),
                                 fmaf(fmaxf(rv.y, 0.f), w2, b2));
        }
    }
    __syncthreads();

    const float2* kv2 = (const float2*)ldsKV;
    float km = -INFINITY, kn = INFINITY;
    for (int idx = tid; idx < ND; idx += 256) {
        float2 f = kv2[idx];
        km = fmaxf(km, f.x);
        kn = fminf(kn, f.x);
    }
#pragma unroll
    for (int off = 1; off < 64; off <<= 1) {
        km = fmaxf(km, __shfl_xor(km, off));
        kn = fminf(kn, __shfl_xor(kn, off));
    }
    if (ii == 0) { rmax[w] = km; rmin[w] = kn; }
    __syncthreads();
    km = fmaxf(fmaxf(rmax[0], rmax[1]), fmaxf(rmax[2], rmax[3]));
    kn = fminf(fminf(rmin[0], rmin[1]), fminf(rmin[2], rmin[3]));

    float qi = 0.f;
    if (i < ND)
        qi = fmaf(fmaxf(q[(size_t)b * ND + i], 0.f), ipw[0], ipb[0]);
    float m = (qi >= 0.f) ? qi * km : qi * kn;

    int jb = w * 250;
    float den = 0.f, num = 0.f;
#pragma unroll 2
    for (int jl = 0; jl < 250; ++jl) {
        float2 f = kv2[jb + jl];
        float e  = __expf(fmaf(qi, f.x, -m));
        den += e;
        num = fmaf(e, f.y, num);
    }
    sden[tid] = den;
    snum[tid] = num;
    __syncthreads();
    if (w == 0 && i < ND) {
        float dt = sden[ii] + sden[64 + ii] + sden[128 + ii] + sden[192 + ii];
        float nt = snum[ii] + snum[64 + ii] + snum[128 + ii] + snum[192 + ii];
        cfT[(size_t)i * 64 + b] = (nt / dt) * opw[0] + opb[0];
    }
}

// ---------------- K4: out GEMM split-K -> atomic into out -------------------
__global__ __launch_bounds__(256) void k_out(
    const float* __restrict__ cfT, const float* __restrict__ W,
    float* __restrict__ out)
{
    __shared__ float lds[9216];
    int dgx   = blockIdx.x;
    int chunk = blockIdx.y;
    int j0 = chunk * CKO;
    int jc = (ND - j0 < CKO) ? (ND - j0) : CKO;
    const float* Asrc = cfT + (size_t)j0 * 64;
    gemm_tile<CKO>(Asrc, W, ND, dgx * 64, j0, jc, out, ND, 1, 0, lds);
}

extern "C" void kernel_launch(void* const* d_in, const int* in_sizes, int n_in,
                              void* d_out, int out_size, void* d_ws, size_t ws_size,
                              hipStream_t stream)
{
    const float* x    = (const float*)d_in[0];
    const float* g    = (const float*)d_in[1];
    const float* be   = (const float*)d_in[2];
    const float* mu   = (const float*)d_in[3];
    const float* va   = (const float*)d_in[4];
    const float* cwq  = (const float*)d_in[5];
    const float* cbq  = (const float*)d_in[6];
    const float* lwq  = (const float*)d_in[7];
    const float* lbq  = (const float*)d_in[8];
    const float* cwk  = (const float*)d_in[9];
    const float* cbk  = (const float*)d_in[10];
    const float* lwk  = (const float*)d_in[11];
    const float* lbk  = (const float*)d_in[12];
    const float* cwv  = (const float*)d_in[13];
    const float* cbv  = (const float*)d_in[14];
    const float* lwv  = (const float*)d_in[15];
    const float* lbv  = (const float*)d_in[16];
    const float* ipw  = (const float*)d_in[17];
    const float* ipb  = (const float*)d_in[18];
    const float* opw  = (const float*)d_in[19];
    const float* opb  = (const float*)d_in[20];
    const float* W    = (const float*)d_in[21];
    const float* outb = (const float*)d_in[22];

    float* ws    = (float*)d_ws;
    float* convT = ws + OFF_CONVT;
    float* q     = ws + OFF_Q;
    float* kv    = ws + OFF_KV;
    float* cfT   = ws + OFF_CF;
    float* out   = (float*)d_out;

    k_bnconv<<<dim3(4, 64), 256, 0, stream>>>(x, g, be, mu, va,
                                              cwq, cbq, cwk, cbk, cwv, cbv,
                                              lbq, lbk, lbv, outb,
                                              convT, q, kv, out);
    k_lin   <<<dim3(16, 3, NCHL), 256, 0, stream>>>(convT, lwq, lwk, lwv, q, kv);
    k_attn  <<<dim3(16, 64), 256, 0, stream>>>(q, kv, ipw, ipb, opw, opb, cfT);
    k_out   <<<dim3(16, NCHO), 256, 0, stream>>>(cfT, W, out);
}

// Round 5
// 168.538 us; speedup vs baseline: 1.6650x; 1.6650x over previous
//
#include <hip/hip_runtime.h>
#include <math.h>

#define NB 64
#define LIN 4001
#define LC 998
#define ND 1000
#define EPSBN 1e-5f

#define CKL 100          // K-chunk for QKV GEMM -> 10 chunks * 48 = 480 blocks
#define NCHL 10
#define CKO 50           // K-chunk for out GEMM -> 20 chunks * 16 = 320 blocks
#define NCHO 20

// ws float offsets
#define OFF_CONVT 0u          // 3*998*64     = 191616
#define OFF_PP    191616u     // 10*3*16*4096 = 1966080
#define OFF_Q     2157696u    // 64*1000      = 64000
#define OFF_KV    2221696u    // 64*2048      = 131072
#define OFF_CF    2352768u    // 1000*64      = 64000
#define OFF_OP    2416768u    // 20*16*4096   = 1310720
// end = 3727488 floats = 14.9 MB

// ---------------- K1: fused BatchNorm + strided conv -> convT[w][j][b] ------
__global__ __launch_bounds__(256) void k_bnconv(
    const float* __restrict__ x,
    const float* __restrict__ g, const float* __restrict__ be,
    const float* __restrict__ mu, const float* __restrict__ va,
    const float* __restrict__ cwq, const float* __restrict__ cbq,
    const float* __restrict__ cwk, const float* __restrict__ cbk,
    const float* __restrict__ cwv, const float* __restrict__ cbv,
    float* __restrict__ convT)
{
    int j = blockIdx.x * 256 + threadIdx.x;
    int b = blockIdx.y;
    if (j >= LC) return;
    const float* xb = x + (size_t)b * LIN + 4 * j;
    float aq = 0.f, ak = 0.f, av = 0.f;
#pragma unroll
    for (int t = 0; t < 10; ++t) {
        int i = 4 * j + t;
        float s  = g[i] * rsqrtf(va[i] + EPSBN);
        float xn = (xb[t] - mu[i]) * s + be[i];
        aq = fmaf(xn, cwq[t], aq);
        ak = fmaf(xn, cwk[t], ak);
        av = fmaf(xn, cwv[t], av);
    }
    convT[((size_t)0 * LC + j) * 64 + b] = aq + cbq[0];
    convT[((size_t)1 * LC + j) * 64 + b] = ak + cbk[0];
    convT[((size_t)2 * LC + j) * 64 + b] = av + cbv[0];
}

// ---------------- shared GEMM microtile body (64b x 64d x CKT) --------------
template <int CKT>
__device__ __forceinline__ void gemm_tile(
    const float* __restrict__ Asrc,   // [jc][64] chunk, b-contiguous
    const float* __restrict__ Brow,   // weight base, row stride ldB
    int ldB, int dgb, int j0, int jc,
    float* __restrict__ Pt,           // output tile [64 b][64 d]
    float* lds)
{
    constexpr int LDW = CKT + 1;
    constexpr int F2R = CKT / 2;
    float* ldsC = lds;                // [CKT][64]
    float* ldsW = lds + CKT * 64;     // [64][LDW]
    int tid  = threadIdx.x;
    int lane = tid & 63;
    int w    = tid >> 6;
    int b0   = (lane & 7) << 3;
    int d0   = (lane >> 3) << 3;

    {   // stage A chunk via float4 (fully coalesced)
        const float4* src = (const float4*)Asrc;
        float4* dst = (float4*)ldsC;
        int n = jc * 16;
        for (int t = tid; t < n; t += 256) dst[t] = src[t];
    }
    // stage B tile via float2 (row starts & j0 are even)
    for (int idx = tid; idx < 64 * F2R; idx += 256) {
        int dd = idx / F2R, j2 = idx % F2R;
        int dg = dgb + dd;
        float2 v = make_float2(0.f, 0.f);
        if (dg < ND && 2 * j2 < jc)
            v = *(const float2*)(Brow + (size_t)dg * ldB + j0 + 2 * j2);
        ldsW[dd * LDW + 2 * j2]     = v.x;
        ldsW[dd * LDW + 2 * j2 + 1] = v.y;
    }
    __syncthreads();

    float acc[8][8];
#pragma unroll
    for (int i = 0; i < 8; ++i)
#pragma unroll
        for (int jx = 0; jx < 8; ++jx) acc[i][jx] = 0.f;

    int js = (jc * w) >> 2;
    int je = (jc * (w + 1)) >> 2;
    for (int jj = js; jj < je; ++jj) {
        float4 c0 = *(const float4*)(ldsC + jj * 64 + b0);
        float4 c1 = *(const float4*)(ldsC + jj * 64 + b0 + 4);
        float cv[8] = {c0.x, c0.y, c0.z, c0.w, c1.x, c1.y, c1.z, c1.w};
        float wv[8];
#pragma unroll
        for (int r = 0; r < 8; ++r) wv[r] = ldsW[(d0 + r) * LDW + jj];
#pragma unroll
        for (int i = 0; i < 8; ++i)
#pragma unroll
            for (int jx = 0; jx < 8; ++jx)
                acc[i][jx] = fmaf(cv[i], wv[jx], acc[i][jx]);
    }
    __syncthreads();   // done with staged data; reuse LDS for reduce

    // two passes (f4 halves of each lane's d-range); per-wave buf [64][36]
    for (int p = 0; p < 2; ++p) {
        float* red = lds + w * 2304;
#pragma unroll
        for (int i = 0; i < 8; ++i)
            *(float4*)(red + (b0 + i) * 36 + (d0 >> 1)) =
                make_float4(acc[i][4*p], acc[i][4*p+1], acc[i][4*p+2], acc[i][4*p+3]);
        __syncthreads();
        for (int t = tid; t < 512; t += 256) {
            int bb = t >> 3, gg = t & 7;
            int o = bb * 36 + 4 * gg;
            float4 a0 = *(const float4*)(lds + o);
            float4 a1 = *(const float4*)(lds + 2304 + o);
            float4 a2 = *(const float4*)(lds + 4608 + o);
            float4 a3 = *(const float4*)(lds + 6912 + o);
            float4 s;
            s.x = a0.x + a1.x + a2.x + a3.x;
            s.y = a0.y + a1.y + a2.y + a3.y;
            s.z = a0.z + a1.z + a2.z + a3.z;
            s.w = a0.w + a1.w + a2.w + a3.w;
            *(float4*)(Pt + bb * 64 + 8 * gg + 4 * p) = s;
        }
        __syncthreads();
    }
}

// ---------------- K2: QKV GEMM partials -> Pp (no atomics) ------------------
__global__ __launch_bounds__(256) void k_lin(
    const float* __restrict__ convT,
    const float* __restrict__ lwq, const float* __restrict__ lwk,
    const float* __restrict__ lwv,
    float* __restrict__ Pp)
{
    __shared__ float lds[12864];
    int dgb   = blockIdx.x * 64;
    int which = blockIdx.y;
    int chunk = blockIdx.z;
    int j0 = chunk * CKL;
    int jc = (LC - j0 < CKL) ? (LC - j0) : CKL;
    const float* lw = (which == 0) ? lwq : ((which == 1) ? lwk : lwv);
    const float* Asrc = convT + ((size_t)which * LC + j0) * 64;
    float* Pt = Pp + (((size_t)chunk * 3 + which) * 16 + blockIdx.x) * 4096;
    gemm_tile<CKL>(Asrc, lw, LC, dgb, j0, jc, Pt, lds);
}

// ---------------- K3: reduce chunks + bias + ReLU + in_proj -> q, kv --------
__global__ __launch_bounds__(256) void k_act(
    const float* __restrict__ Pp,
    const float* __restrict__ lbq, const float* __restrict__ lbk,
    const float* __restrict__ lbv,
    const float* __restrict__ ipw, const float* __restrict__ ipb,
    float* __restrict__ q, float* __restrict__ kv)
{
    int i = blockIdx.x * 256 + threadIdx.x;
    int b = blockIdx.y;
    if (i >= ND) return;
    int it = i >> 6, il = i & 63;
    float s0 = 0.f, s1 = 0.f, s2 = 0.f;
    for (int c = 0; c < NCHL; ++c) {
        size_t base = (((size_t)c * 3) * 16 + it) * 4096 + (il | (b << 6));
        s0 += Pp[base];
        s1 += Pp[base + 16 * 4096];
        s2 += Pp[base + 32 * 4096];
    }
    float yq = fmaxf(s0 + lbq[i], 0.f) * ipw[0] + ipb[0];
    float yk = fmaxf(s1 + lbk[i], 0.f) * ipw[1] + ipb[1];
    float yv = fmaxf(s2 + lbv[i], 0.f) * ipw[2] + ipb[2];
    q[(size_t)b * ND + i] = yq;
    kv[(size_t)b * 2048 + 2 * i]     = yk;
    kv[(size_t)b * 2048 + 2 * i + 1] = yv;
}

// ---------------- K4: attention, 4-way wave K-split, writes cfT[i][b] -------
__global__ __launch_bounds__(256) void k_attn(
    const float* __restrict__ q, const float* __restrict__ kv,
    const float* __restrict__ opw, const float* __restrict__ opb,
    float* __restrict__ cfT)
{
    __shared__ float ldsKV[2048];
    __shared__ float sden[256];
    __shared__ float snum[256];
    __shared__ float rmax[4];
    __shared__ float rmin[4];
    int tid = threadIdx.x;
    int b   = blockIdx.y;
    int w   = tid >> 6;           // wave id (uniform)
    int ii  = tid & 63;
    int i   = blockIdx.x * 64 + ii;

    {   // stage kv[b] (8 KB)
        const float4* src = (const float4*)(kv + (size_t)b * 2048);
        float4* dst = (float4*)ldsKV;
        for (int t = tid; t < 512; t += 256) dst[t] = src[t];
    }
    __syncthreads();

    const float2* kv2 = (const float2*)ldsKV;
    float km = -INFINITY, kn = INFINITY;
    for (int idx = tid; idx < ND; idx += 256) {
        float2 f = kv2[idx];
        km = fmaxf(km, f.x);
        kn = fminf(kn, f.x);
    }
#pragma unroll
    for (int off = 1; off < 64; off <<= 1) {
        km = fmaxf(km, __shfl_xor(km, off));
        kn = fminf(kn, __shfl_xor(kn, off));
    }
    if (ii == 0) { rmax[w] = km; rmin[w] = kn; }
    __syncthreads();
    km = fmaxf(fmaxf(rmax[0], rmax[1]), fmaxf(rmax[2], rmax[3]));
    kn = fminf(fminf(rmin[0], rmin[1]), fminf(rmin[2], rmin[3]));

    float qi = (i < ND) ? q[(size_t)b * ND + i] : 0.f;
    float m  = (qi >= 0.f) ? qi * km : qi * kn;

    int jb = w * 250;
    float den = 0.f, num = 0.f;
#pragma unroll 2
    for (int jl = 0; jl < 250; ++jl) {
        float2 f = kv2[jb + jl];
        float e  = __expf(fmaf(qi, f.x, -m));
        den += e;
        num = fmaf(e, f.y, num);
    }
    sden[tid] = den;
    snum[tid] = num;
    __syncthreads();
    if (w == 0 && i < ND) {
        float dt = sden[ii] + sden[64 + ii] + sden[128 + ii] + sden[192 + ii];
        float nt = snum[ii] + snum[64 + ii] + snum[128 + ii] + snum[192 + ii];
        cfT[(size_t)i * 64 + b] = (nt / dt) * opw[0] + opb[0];
    }
}

// ---------------- K5: out GEMM partials -> Op (no atomics) ------------------
__global__ __launch_bounds__(256) void k_out(
    const float* __restrict__ cfT, const float* __restrict__ W,
    float* __restrict__ Op)
{
    __shared__ float lds[9216];   // staging 6464 < reduce 9216
    int egb   = blockIdx.x * 64;
    int chunk = blockIdx.y;
    int j0 = chunk * CKO;
    int jc = (ND - j0 < CKO) ? (ND - j0) : CKO;
    const float* Asrc = cfT + (size_t)j0 * 64;
    float* Pt = Op + ((size_t)chunk * 16 + blockIdx.x) * 4096;
    gemm_tile<CKO>(Asrc, W, ND, egb, j0, jc, Pt, lds);
}

// ---------------- K6: reduce Op chunks + bias -> out ------------------------
__global__ __launch_bounds__(256) void k_fin(
    const float* __restrict__ Op, const float* __restrict__ outb,
    float* __restrict__ out)
{
    int e = blockIdx.x * 256 + threadIdx.x;
    int b = blockIdx.y;
    if (e >= ND) return;
    float s = outb[e];
    size_t cell = ((size_t)(e >> 6)) * 4096 + (b << 6) + (e & 63);
    for (int c = 0; c < NCHO; ++c)
        s += Op[(size_t)c * 16 * 4096 + cell];
    out[(size_t)b * ND + e] = s;
}

extern "C" void kernel_launch(void* const* d_in, const int* in_sizes, int n_in,
                              void* d_out, int out_size, void* d_ws, size_t ws_size,
                              hipStream_t stream)
{
    const float* x    = (const float*)d_in[0];
    const float* g    = (const float*)d_in[1];
    const float* be   = (const float*)d_in[2];
    const float* mu   = (const float*)d_in[3];
    const float* va   = (const float*)d_in[4];
    const float* cwq  = (const float*)d_in[5];
    const float* cbq  = (const float*)d_in[6];
    const float* lwq  = (const float*)d_in[7];
    const float* lbq  = (const float*)d_in[8];
    const float* cwk  = (const float*)d_in[9];
    const float* cbk  = (const float*)d_in[10];
    const float* lwk  = (const float*)d_in[11];
    const float* lbk  = (const float*)d_in[12];
    const float* cwv  = (const float*)d_in[13];
    const float* cbv  = (const float*)d_in[14];
    const float* lwv  = (const float*)d_in[15];
    const float* lbv  = (const float*)d_in[16];
    const float* ipw  = (const float*)d_in[17];
    const float* ipb  = (const float*)d_in[18];
    const float* opw  = (const float*)d_in[19];
    const float* opb  = (const float*)d_in[20];
    const float* W    = (const float*)d_in[21];
    const float* outb = (const float*)d_in[22];

    float* ws    = (float*)d_ws;
    float* convT = ws + OFF_CONVT;
    float* Pp    = ws + OFF_PP;
    float* q     = ws + OFF_Q;
    float* kv    = ws + OFF_KV;
    float* cfT   = ws + OFF_CF;
    float* Op    = ws + OFF_OP;
    float* out   = (float*)d_out;

    k_bnconv<<<dim3(4, 64), 256, 0, stream>>>(x, g, be, mu, va,
                                              cwq, cbq, cwk, cbk, cwv, cbv, convT);
    k_lin  <<<dim3(16, 3, NCHL), 256, 0, stream>>>(convT, lwq, lwk, lwv, Pp);
    k_act  <<<dim3(4, 64), 256, 0, stream>>>(Pp, lbq, lbk, lbv, ipw, ipb, q, kv);
    k_attn <<<dim3(16, 64), 256, 0, stream>>>(q, kv, opw, opb, cfT);
    k_out  <<<dim3(16, NCHO), 256, 0, stream>>>(cfT, W, Op);
    k_fin  <<<dim3(4, 64), 256, 0, stream>>>(Op, outb, out);
}